// Round 1
// baseline (89.899 us; speedup 1.0000x reference)
//
#include <hip/hip_runtime.h>

#define PAD 4
#define B_ 64
#define C_ 9
#define H_ 256
#define W_ 256
#define HP (H_ + 2*PAD)   // 264
#define WP (W_ + 2*PAD)   // 264

// One block = one output row (b,c,i). One thread = one output pixel j.
// out[b,c,i,j] = sum_{a,d in {0,1}} wy_d * wx_a * valid * x_pad[y_d][x_a]
// where x_pad is replicate-padded x (handled by clamped indexing) and the
// valid mask implements grid_sample zeros-padding against the padded extent.
__global__ __launch_bounds__(256) void RandomShiftsAug_kernel(
    const float* __restrict__ x,
    const int* __restrict__ shift_x,
    const int* __restrict__ shift_y,
    float* __restrict__ out)
{
    const int row = blockIdx.x;          // 0 .. B*C*H-1
    const int j   = threadIdx.x;         // output column
    const int i   = row & (H_ - 1);      // output row within plane
    const int bc  = row >> 8;            // b*C + c
    const int b   = bc / C_;

    // Mirror reference coordinate arithmetic (fp32):
    // gx = linspace(-1+eps, 1-eps, W) ; gxb = gx + sx*(2/wp)
    // ix = ((gxb+1)*wp - 1) * 0.5
    const float eps   = 2.0f / 264.0f;
    const float stepc = (2.0f - 2.0f * eps) / 255.0f;

    const float sx = (float)shift_x[b];
    const float sy = (float)shift_y[b];

    const float gx = -1.0f + eps + (float)j * stepc + sx * (2.0f / 264.0f);
    const float gy = -1.0f + eps + (float)i * stepc + sy * (2.0f / 264.0f);
    const float ix = ((gx + 1.0f) * 264.0f - 1.0f) * 0.5f;
    const float iy = ((gy + 1.0f) * 264.0f - 1.0f) * 0.5f;

    const float fx0 = floorf(ix), fy0 = floorf(iy);
    float wx1 = ix - fx0, wy1 = iy - fy0;
    float wx0 = 1.0f - wx1, wy0 = 1.0f - wy1;

    const int px0 = (int)fx0, py0 = (int)fy0;
    const int px1 = px0 + 1,  py1 = py0 + 1;

    // zeros-padding validity vs padded extent [0, 263]
    if (px0 < 0 || px0 > WP - 1) wx0 = 0.0f;
    if (px1 < 0 || px1 > WP - 1) wx1 = 0.0f;
    if (py0 < 0 || py0 > HP - 1) wy0 = 0.0f;
    if (py1 < 0 || py1 > HP - 1) wy1 = 0.0f;

    // padded coord -> source coord with replicate clamp
    const int cx0 = min(max(px0 - PAD, 0), W_ - 1);
    const int cx1 = min(max(px1 - PAD, 0), W_ - 1);
    const int cy0 = min(max(py0 - PAD, 0), H_ - 1);
    const int cy1 = min(max(py1 - PAD, 0), H_ - 1);

    const float* __restrict__ plane = x + (size_t)bc * (size_t)(H_ * W_);
    const float v00 = plane[cy0 * W_ + cx0];
    const float v01 = plane[cy0 * W_ + cx1];
    const float v10 = plane[cy1 * W_ + cx0];
    const float v11 = plane[cy1 * W_ + cx1];

    const float r0 = v00 * wx0 + v01 * wx1;
    const float r1 = v10 * wx0 + v11 * wx1;
    out[(size_t)row * W_ + j] = r0 * wy0 + r1 * wy1;
}

extern "C" void kernel_launch(void* const* d_in, const int* in_sizes, int n_in,
                              void* d_out, int out_size, void* d_ws, size_t ws_size,
                              hipStream_t stream) {
    const float* x       = (const float*)d_in[0];
    const int*   shift_x = (const int*)d_in[1];
    const int*   shift_y = (const int*)d_in[2];
    float*       out     = (float*)d_out;

    const int rows = B_ * C_ * H_;   // 147456 blocks
    RandomShiftsAug_kernel<<<rows, W_, 0, stream>>>(x, shift_x, shift_y, out);
}

// Round 2
// 72.196 us; speedup vs baseline: 1.2452x; 1.2452x over previous
//
#include <hip/hip_runtime.h>

#define PAD 4
#define B_ 64
#define C_ 9
#define H_ 256
#define W_ 256
#define HPAD 264   // padded extent (both axes)

// One wave = one full output row (b,c,i). Lane l handles columns
// {l, l+64, l+128, l+192} (interleaved -> every load/store instruction is
// near-perfectly coalesced). Block = 4 waves = 4 consecutive rows of the
// same (b,c) plane, so bc/b/shift loads are block-uniform (scalarized).
//
// Coordinate math (algebraically identical to the reference):
//   ix = 0.5 + shift_x[b] + j * (262/255), same for iy with row index i.
// zeros-padding validity is vs the padded extent [0, 263]; replicate pad is
// a clamp into [0, 255] after subtracting PAD.
__global__ __launch_bounds__(256) void RandomShiftsAug_kernel(
    const float* __restrict__ x,
    const int* __restrict__ shift_x,
    const int* __restrict__ shift_y,
    float* __restrict__ out)
{
    const int tid  = threadIdx.x;
    const int lane = tid & 63;
    const int wv   = tid >> 6;
    const int r    = (blockIdx.x << 2) + wv;   // global output row id
    const int i    = r & (H_ - 1);             // row within plane
    const int bc   = (blockIdx.x << 2) >> 8;   // block-uniform plane id
    const int b    = bc / C_;                  // block-uniform -> scalar div

    const float STEP = 262.0f / 255.0f;

    const float sx = (float)shift_x[b];
    const float sy = (float)shift_y[b];

    // ---- y side (wave-uniform) ----
    const float iy  = fmaf((float)i, STEP, 0.5f + sy);
    const float fy0 = floorf(iy);
    float wy1 = iy - fy0;
    float wy0 = 1.0f - wy1;
    const int py0 = (int)fy0;
    const int py1 = py0 + 1;
    if ((unsigned)py0 > (unsigned)(HPAD - 1)) wy0 = 0.0f;
    if ((unsigned)py1 > (unsigned)(HPAD - 1)) wy1 = 0.0f;
    const int cy0 = min(max(py0 - PAD, 0), H_ - 1);
    const int cy1 = min(max(py1 - PAD, 0), H_ - 1);

    const float* __restrict__ plane = x + (size_t)bc * (size_t)(H_ * W_);
    const float* __restrict__ row0  = plane + cy0 * W_;
    const float* __restrict__ row1  = plane + cy1 * W_;
    float* __restrict__ orow        = out + (size_t)r * W_;

    // ---- x side: 4 interleaved columns per lane ----
    const float xbase = 0.5f + sx;

    #pragma unroll
    for (int k = 0; k < 4; ++k) {
        const int   j   = lane + 64 * k;
        const float ix  = fmaf((float)j, STEP, xbase);
        const float fx0 = floorf(ix);
        float wx1 = ix - fx0;
        float wx0 = 1.0f - wx1;
        const int px0 = (int)fx0;
        const int px1 = px0 + 1;
        if ((unsigned)px0 > (unsigned)(HPAD - 1)) wx0 = 0.0f;
        if ((unsigned)px1 > (unsigned)(HPAD - 1)) wx1 = 0.0f;
        const int cx0 = min(max(px0 - PAD, 0), W_ - 1);
        const int cx1 = min(max(px1 - PAD, 0), W_ - 1);

        const float v00 = row0[cx0];
        const float v01 = row0[cx1];
        const float v10 = row1[cx0];
        const float v11 = row1[cx1];

        const float r0 = fmaf(v00, wx0, v01 * wx1);
        const float r1 = fmaf(v10, wx0, v11 * wx1);
        orow[j] = fmaf(r0, wy0, r1 * wy1);
    }
}

extern "C" void kernel_launch(void* const* d_in, const int* in_sizes, int n_in,
                              void* d_out, int out_size, void* d_ws, size_t ws_size,
                              hipStream_t stream) {
    const float* x       = (const float*)d_in[0];
    const int*   shift_x = (const int*)d_in[1];
    const int*   shift_y = (const int*)d_in[2];
    float*       out     = (float*)d_out;

    const int blocks = (B_ * C_ * H_) / 4;   // 36864 blocks, 4 rows each
    RandomShiftsAug_kernel<<<blocks, 256, 0, stream>>>(x, shift_x, shift_y, out);
}

// Round 3
// 54.466 us; speedup vs baseline: 1.6505x; 1.3255x over previous
//
#include <hip/hip_runtime.h>

#define PAD 4
#define B_ 64
#define C_ 9
#define H_ 256
#define W_ 256
#define PEXT 264          // padded extent (both axes)
#define TILE_R 16         // output rows per block
#define SROWS 18          // staged padded rows per block (16*1.0275+2 -> <=18)
#define LROW 268          // LDS row stride in dwords (265 used; 268 keeps 16B align)

// Block = 16 output rows x 256 cols of one (b,c) plane.
// Stage <=18 source rows into LDS as x-replicate-padded rows (cols 0..264 in
// padded coords), then each tap is an LDS read pair (c, c+1) -> ds_read2_b32.
// y replicate-pad handled by clamping the staged source row; grid_sample
// zeros-padding handled by zeroing weights vs padded extent [0,263].
// Coordinate math identical to rounds 1-2: ix = 0.5 + shift + j*(262/255).
__global__ __launch_bounds__(256) void RandomShiftsAug_kernel(
    const float* __restrict__ x,
    const int* __restrict__ shift_x,
    const int* __restrict__ shift_y,
    float* __restrict__ out)
{
    __shared__ float sm[SROWS * LROW];   // 19296 B

    const int tid  = threadIdx.x;
    const int lane = tid & 63;
    const int wv   = tid >> 6;

    const int bc   = blockIdx.x >> 4;    // plane id (b*C + c)
    const int rblk = blockIdx.x & 15;
    const int i0   = rblk << 4;          // first output row of tile
    const int b    = bc / C_;

    const float STEP = 262.0f / 255.0f;
    const float sx = (float)shift_x[b];
    const float sy = (float)shift_y[b];
    const float xbase = 0.5f + sx;
    const float ybase = 0.5f + sy;

    // first padded source row needed by this tile (block-uniform)
    const int sr_base = (int)floorf(fmaf((float)i0, STEP, ybase));

    const float* __restrict__ plane = x + (size_t)bc * (size_t)(H_ * W_);

    // ---- stage SROWS rows: interior padded cols 4..259 via global_load_lds ----
    for (int s = wv; s < SROWS; s += 4) {
        const int rs = min(max(sr_base + s - PAD, 0), H_ - 1);
        const float* src = plane + rs * W_ + lane * 4;      // 16B per lane
        float* dst = &sm[s * LROW + 4];                      // 16B-aligned base
        __builtin_amdgcn_global_load_lds(
            (const __attribute__((address_space(1))) void*)src,
            (__attribute__((address_space(3))) void*)dst,
            16, 0, 0);
    }
    __syncthreads();   // compiler drains vmcnt(0) before barrier

    // ---- replicate-fill x edges: padded cols 0..3 and 260..264 ----
    if (tid < SROWS * 9) {
        const int s = tid / 9;
        const int e = tid - s * 9;
        const int p    = (e < 4) ? e : (256 + e);   // 0..3 | 260..264
        const int srcd = (e < 4) ? 4 : 259;         // row[0] | row[255]
        sm[s * LROW + p] = sm[s * LROW + srcd];
    }
    __syncthreads();

    // ---- per-lane x-side precompute (4 interleaved cols, reused for 4 rows) ----
    float wx0[4], wx1[4];
    int rdc[4];
    #pragma unroll
    for (int c = 0; c < 4; ++c) {
        const int j   = lane + 64 * c;
        const float ixv = fmaf((float)j, STEP, xbase);
        const float fx  = floorf(ixv);
        const int   px0 = (int)fx;
        float w1 = ixv - fx;
        float w0 = 1.0f - w1;
        if (px0 > PEXT - 1)     w0 = 0.0f;   // zeros padding (px0 >= 0 always)
        if (px0 + 1 > PEXT - 1) w1 = 0.0f;
        wx0[c] = w0;
        wx1[c] = w1;
        rdc[c] = min(px0, PEXT - 1);          // clamped read col (pad col 264 is finite)
    }

    // ---- compute 4 rows per wave, 4 cols per lane ----
    #pragma unroll
    for (int m = 0; m < 4; ++m) {
        const int i = i0 + wv * 4 + m;                      // wave-uniform row
        const float iyv = fmaf((float)i, STEP, ybase);
        const float fy  = floorf(iyv);
        const int   py0 = (int)fy;
        float wy1 = iyv - fy;
        float wy0 = 1.0f - wy1;
        if (py0 > PEXT - 1)     wy0 = 0.0f;
        if (py0 + 1 > PEXT - 1) wy1 = 0.0f;
        const int s0 = py0 - sr_base;                       // in [0,16]
        const float* __restrict__ r0p = &sm[s0 * LROW];
        const float* __restrict__ r1p = r0p + LROW;
        float* __restrict__ orow = out + ((size_t)(bc * H_ + i)) * (size_t)W_;

        #pragma unroll
        for (int c = 0; c < 4; ++c) {
            const int rd = rdc[c];
            const float v00 = r0p[rd], v01 = r0p[rd + 1];   // ds_read2_b32
            const float v10 = r1p[rd], v11 = r1p[rd + 1];   // ds_read2_b32
            const float a0 = fmaf(v00, wx0[c], v01 * wx1[c]);
            const float a1 = fmaf(v10, wx0[c], v11 * wx1[c]);
            orow[lane + 64 * c] = fmaf(a0, wy0, a1 * wy1);
        }
    }
}

extern "C" void kernel_launch(void* const* d_in, const int* in_sizes, int n_in,
                              void* d_out, int out_size, void* d_ws, size_t ws_size,
                              hipStream_t stream) {
    const float* x       = (const float*)d_in[0];
    const int*   shift_x = (const int*)d_in[1];
    const int*   shift_y = (const int*)d_in[2];
    float*       out     = (float*)d_out;

    const int blocks = B_ * C_ * (H_ / TILE_R);   // 9216
    RandomShiftsAug_kernel<<<blocks, 256, 0, stream>>>(x, shift_x, shift_y, out);
}

// Round 4
// 52.347 us; speedup vs baseline: 1.7174x; 1.0405x over previous
//
#include <hip/hip_runtime.h>

#define PAD 4
#define B_ 64
#define C_ 9
#define H_ 256
#define W_ 256
#define PEXT 264          // padded extent (both axes)
#define TILE_R 16         // output rows per block
#define SROWS 18          // max staged padded rows per block
#define LROW 268          // LDS row stride in dwords (265 used; keeps 16B align)
#define NBLK (B_ * C_ * (H_ / TILE_R))   // 9216, divisible by 8

// Block = 16 output rows x 256 cols of one (b,c) plane.
// Stage srows (17 or 18, computed exactly) source rows into LDS as
// x-replicate-padded rows via global_load_lds (interior) + global edge loads
// (pad cols, issued in the same phase -> ONE barrier). Taps are ds_read2_b32.
// XCD-bijective blockIdx swizzle keeps a plane's tiles on one XCD so the
// ~1.5-row staging overlap between adjacent tiles hits L2.
// Coordinate math identical to rounds 1-3: ix = 0.5 + shift + j*(262/255).
__global__ __launch_bounds__(256) void RandomShiftsAug_kernel(
    const float* __restrict__ x,
    const int* __restrict__ shift_x,
    const int* __restrict__ shift_y,
    float* __restrict__ out)
{
    __shared__ float sm[SROWS * LROW];   // 19296 B -> 8 blocks/CU

    const int tid  = threadIdx.x;
    const int lane = tid & 63;
    const int wv   = tid >> 6;

    // XCD-aware bijective swizzle: physical XCD = blockIdx % 8 (round-robin);
    // give each XCD a contiguous chunk of work ids -> adjacent tiles co-XCD.
    const int wid  = (blockIdx.x & 7) * (NBLK / 8) + (blockIdx.x >> 3);

    const int bc   = wid >> 4;           // plane id (b*C + c)
    const int rblk = wid & 15;
    const int i0   = rblk << 4;          // first output row of tile
    const int b    = bc / C_;

    const float STEP = 262.0f / 255.0f;
    const float sx = (float)shift_x[b];
    const float sy = (float)shift_y[b];
    const float xbase = 0.5f + sx;
    const float ybase = 0.5f + sy;

    // staged padded-row range needed by this tile (block-uniform)
    const int sr_base = (int)floorf(fmaf((float)i0, STEP, ybase));
    const int sr_last = (int)floorf(fmaf((float)(i0 + TILE_R - 1), STEP, ybase)) + 1;
    const int srows   = sr_last - sr_base + 1;   // 17 or 18

    const float* __restrict__ plane = x + (size_t)bc * (size_t)(H_ * W_);

    // ---- stage interior padded cols 4..259 via global_load_lds (16B/lane) ----
    for (int s = wv; s < srows; s += 4) {
        const int rs = min(max(sr_base + s - PAD, 0), H_ - 1);
        const float* src = plane + rs * W_ + lane * 4;
        float* dst = &sm[s * LROW + 4];
        __builtin_amdgcn_global_load_lds(
            (const __attribute__((address_space(1))) void*)src,
            (__attribute__((address_space(3))) void*)dst,
            16, 0, 0);
    }

    // ---- x-edge replicate pads from GLOBAL (L2-hot), same phase ----
    // padded cols 0..3 <- src col 0 ; padded cols 260..264 <- src col 255
    if (tid < srows * 9) {
        const int s = tid / 9;
        const int e = tid - s * 9;
        const int rs = min(max(sr_base + s - PAD, 0), H_ - 1);
        const int p    = (e < 4) ? e : (256 + e);     // 0..3 | 260..264
        const int srcc = (e < 4) ? 0 : (W_ - 1);
        sm[s * LROW + p] = plane[rs * W_ + srcc];
    }
    __syncthreads();   // drains vmcnt (global_load_lds) + lgkmcnt (ds_write)

    // ---- per-lane x-side precompute (4 interleaved cols, reused for 4 rows) ----
    float wx0[4], wx1[4];
    int rdc[4];
    #pragma unroll
    for (int c = 0; c < 4; ++c) {
        const int j   = lane + 64 * c;
        const float ixv = fmaf((float)j, STEP, xbase);
        const float fx  = floorf(ixv);
        const int   px0 = (int)fx;
        float w1 = ixv - fx;
        float w0 = 1.0f - w1;
        if (px0 > PEXT - 1)     w0 = 0.0f;   // zeros padding (px0 >= 0 always)
        if (px0 + 1 > PEXT - 1) w1 = 0.0f;
        wx0[c] = w0;
        wx1[c] = w1;
        rdc[c] = min(px0, PEXT - 1);          // clamped read col
    }

    // ---- compute 4 rows per wave, 4 cols per lane ----
    #pragma unroll
    for (int m = 0; m < 4; ++m) {
        const int i = i0 + wv * 4 + m;                      // wave-uniform row
        const float iyv = fmaf((float)i, STEP, ybase);
        const float fy  = floorf(iyv);
        const int   py0 = (int)fy;
        float wy1 = iyv - fy;
        float wy0 = 1.0f - wy1;
        if (py0 > PEXT - 1)     wy0 = 0.0f;
        if (py0 + 1 > PEXT - 1) wy1 = 0.0f;
        const int s0 = py0 - sr_base;                       // reads stay < srows
        const float* __restrict__ r0p = &sm[s0 * LROW];
        const float* __restrict__ r1p = r0p + LROW;
        float* __restrict__ orow = out + ((size_t)(bc * H_ + i)) * (size_t)W_;

        #pragma unroll
        for (int c = 0; c < 4; ++c) {
            const int rd = rdc[c];
            const float v00 = r0p[rd], v01 = r0p[rd + 1];   // ds_read2_b32
            const float v10 = r1p[rd], v11 = r1p[rd + 1];   // ds_read2_b32
            const float a0 = fmaf(v00, wx0[c], v01 * wx1[c]);
            const float a1 = fmaf(v10, wx0[c], v11 * wx1[c]);
            orow[lane + 64 * c] = fmaf(a0, wy0, a1 * wy1);
        }
    }
}

extern "C" void kernel_launch(void* const* d_in, const int* in_sizes, int n_in,
                              void* d_out, int out_size, void* d_ws, size_t ws_size,
                              hipStream_t stream) {
    const float* x       = (const float*)d_in[0];
    const int*   shift_x = (const int*)d_in[1];
    const int*   shift_y = (const int*)d_in[2];
    float*       out     = (float*)d_out;

    RandomShiftsAug_kernel<<<NBLK, 256, 0, stream>>>(x, shift_x, shift_y, out);
}